// Round 1
// baseline (937.440 us; speedup 1.0000x reference)
//
#include <hip/hip_runtime.h>

#define BATCH 512
#define NPART 60
#define PFEAT 20
#define SFEAT 14
#define NVTX  5
#define HID   60
#define DE    20
#define DO    24
#define NCLS  2

// ---------------------------------------------------------------------------
// Stage A: per (b,p) layer-1 partials:
//   frA[b,p,:] = xt[b,p] @ fr_w1[0:20]      (receiver part, no bias)
//   frB[b,p,:] = xt[b,p] @ fr_w1[20:40]     (sender part, no bias)
//   pvA[b,p,:] = xt[b,p] @ pv_w1[0:20]      (particle part, no bias)
// xt[b,p,f] = x[(b*PFEAT+f)*NPART + p]
// ---------------------------------------------------------------------------
__global__ __launch_bounds__(64) void stageA_kernel(
    const float* __restrict__ x, const float* __restrict__ fr_w1,
    const float* __restrict__ pv_w1,
    float* __restrict__ frA, float* __restrict__ frB, float* __restrict__ pvA)
{
    int bp = blockIdx.x;                  // b*NPART + p
    int h  = threadIdx.x;
    if (h >= HID) return;
    int b = bp / NPART;
    int p = bp - b * NPART;

    float xr[PFEAT];
#pragma unroll
    for (int f = 0; f < PFEAT; ++f) xr[f] = x[(b*PFEAT + f)*NPART + p];

    float a = 0.f, s = 0.f, c = 0.f;
#pragma unroll
    for (int f = 0; f < PFEAT; ++f) {
        float xv = xr[f];
        a += xv * fr_w1[f*HID + h];
        s += xv * fr_w1[(PFEAT + f)*HID + h];
        c += xv * pv_w1[f*HID + h];
    }
    frA[bp*HID + h] = a;
    frB[bp*HID + h] = s;
    pvA[bp*HID + h] = c;
}

// ---------------------------------------------------------------------------
// Stage A2: per (b,v): pvV[b,v,:] = yt[b,v] @ pv_w1[20:34] + pv_b1
// yt[b,v,f] = y[(b*SFEAT+f)*NVTX + v]
// ---------------------------------------------------------------------------
__global__ __launch_bounds__(64) void stageA2_kernel(
    const float* __restrict__ y, const float* __restrict__ pv_w1,
    const float* __restrict__ pv_b1, float* __restrict__ pvV)
{
    int b = blockIdx.x;
    int h = threadIdx.x;
    if (h >= HID) return;
#pragma unroll
    for (int v = 0; v < NVTX; ++v) {
        float acc = pv_b1[h];
#pragma unroll
        for (int f = 0; f < SFEAT; ++f) {
            acc += y[(b*SFEAT + f)*NVTX + v] * pv_w1[(PFEAT + f)*HID + h];
        }
        pvV[(b*NVTX + v)*HID + h] = acc;
    }
}

// ---------------------------------------------------------------------------
// Stage B: fr edge MLP layers 2,3 + sum over senders.
// One wave per (b,r) group: lane j in [0,59) is sender-slot j, s = j + (j>=r).
// h1 = relu(frA[b,r] + frB[b,s] + fr_b1); h2 = relu(h1@W2+b2); e = relu(h2@W3+b3)
// Ebar_pp[b,r] = sum_j e  (butterfly reduction, lane0 stores -> no atomics)
// ---------------------------------------------------------------------------
__global__ __launch_bounds__(256) void stageB_kernel(
    const float* __restrict__ frA, const float* __restrict__ frB,
    const float* __restrict__ b1g, const float* __restrict__ w2g,
    const float* __restrict__ b2g, const float* __restrict__ w3g,
    const float* __restrict__ b3g, float* __restrict__ Epp)
{
    __shared__ __align__(16) float sw2[HID*HID];
    __shared__ __align__(16) float sw3[HID*DE];
    __shared__ __align__(16) float sb1[HID];
    __shared__ __align__(16) float sb2[HID];
    __shared__ __align__(16) float sb3[DE + 4];   // pad for float4 read of last quad
    for (int i = threadIdx.x; i < HID*HID; i += 256) sw2[i] = w2g[i];
    for (int i = threadIdx.x; i < HID*DE;  i += 256) sw3[i] = w3g[i];
    if (threadIdx.x < HID) { sb1[threadIdx.x] = b1g[threadIdx.x]; sb2[threadIdx.x] = b2g[threadIdx.x]; }
    if (threadIdx.x < DE)  sb3[threadIdx.x] = b3g[threadIdx.x];
    __syncthreads();

    int wave = threadIdx.x >> 6;
    int lane = threadIdx.x & 63;
    int g = blockIdx.x * 4 + wave;        // (b, r)
    int b = g / NPART;
    int r = g - b * NPART;
    int j = lane;
    int s = (j < r) ? j : j + 1;
    if (s >= NPART) s = NPART - 1;        // lanes 59..63 clamped; zeroed below

    const float* fa = frA + (b*NPART + r)*HID;
    const float* fb = frB + (b*NPART + s)*HID;

    float h1[HID];
#pragma unroll
    for (int i = 0; i < HID; i += 4) {
        float4 av = *(const float4*)(fa + i);
        float4 bv = *(const float4*)(fb + i);
        h1[i+0] = fmaxf(av.x + bv.x + sb1[i+0], 0.f);
        h1[i+1] = fmaxf(av.y + bv.y + sb1[i+1], 0.f);
        h1[i+2] = fmaxf(av.z + bv.z + sb1[i+2], 0.f);
        h1[i+3] = fmaxf(av.w + bv.w + sb1[i+3], 0.f);
    }

    float h2[HID];
#pragma unroll
    for (int q = 0; q < HID/4; ++q) {
        float4 acc = *(const float4*)(sb2 + q*4);
#pragma unroll
        for (int i = 0; i < HID; ++i) {
            float4 w = *(const float4*)(sw2 + i*HID + q*4);
            float hv = h1[i];
            acc.x += hv*w.x; acc.y += hv*w.y; acc.z += hv*w.z; acc.w += hv*w.w;
        }
        h2[q*4+0] = fmaxf(acc.x, 0.f);
        h2[q*4+1] = fmaxf(acc.y, 0.f);
        h2[q*4+2] = fmaxf(acc.z, 0.f);
        h2[q*4+3] = fmaxf(acc.w, 0.f);
    }

    float e[DE];
#pragma unroll
    for (int q = 0; q < DE/4; ++q) {
        float4 acc = *(const float4*)(sb3 + q*4);
#pragma unroll
        for (int i = 0; i < HID; ++i) {
            float4 w = *(const float4*)(sw3 + i*DE + q*4);
            float hv = h2[i];
            acc.x += hv*w.x; acc.y += hv*w.y; acc.z += hv*w.z; acc.w += hv*w.w;
        }
        e[q*4+0] = fmaxf(acc.x, 0.f);
        e[q*4+1] = fmaxf(acc.y, 0.f);
        e[q*4+2] = fmaxf(acc.z, 0.f);
        e[q*4+3] = fmaxf(acc.w, 0.f);
    }

    if (j >= NPART - 1) {
#pragma unroll
        for (int k = 0; k < DE; ++k) e[k] = 0.f;
    }

#pragma unroll
    for (int k = 0; k < DE; ++k) {
        float v = e[k];
        v += __shfl_xor(v, 1);
        v += __shfl_xor(v, 2);
        v += __shfl_xor(v, 4);
        v += __shfl_xor(v, 8);
        v += __shfl_xor(v, 16);
        v += __shfl_xor(v, 32);
        e[k] = v;
    }
    if (lane == 0) {
        float* o = Epp + (b*NPART + r)*DE;
#pragma unroll
        for (int k = 0; k < DE; k += 4)
            *(float4*)(o + k) = make_float4(e[k], e[k+1], e[k+2], e[k+3]);
    }
}

// ---------------------------------------------------------------------------
// Stage C: pv edge MLP layers 2,3. Thread per (b,p,v) edge; atomicAdd into Epv.
// h1 = relu(pvA[b,p] + pvV[b,v])   (pvV already holds bias)
// ---------------------------------------------------------------------------
__global__ __launch_bounds__(256) void stageC_kernel(
    const float* __restrict__ pvA, const float* __restrict__ pvV,
    const float* __restrict__ w2g, const float* __restrict__ b2g,
    const float* __restrict__ w3g, const float* __restrict__ b3g,
    float* __restrict__ Epv)
{
    __shared__ __align__(16) float sw2[HID*HID];
    __shared__ __align__(16) float sw3[HID*DE];
    __shared__ __align__(16) float sb2[HID];
    __shared__ __align__(16) float sb3[DE + 4];
    for (int i = threadIdx.x; i < HID*HID; i += 256) sw2[i] = w2g[i];
    for (int i = threadIdx.x; i < HID*DE;  i += 256) sw3[i] = w3g[i];
    if (threadIdx.x < HID) sb2[threadIdx.x] = b2g[threadIdx.x];
    if (threadIdx.x < DE)  sb3[threadIdx.x] = b3g[threadIdx.x];
    __syncthreads();

    int idx = blockIdx.x * 256 + threadIdx.x;   // grid sized exactly BATCH*NPART*NVTX
    int b = idx / (NPART*NVTX);
    int t = idx - b * (NPART*NVTX);
    int p = t / NVTX;
    int v = t - p * NVTX;

    const float* pa = pvA + (b*NPART + p)*HID;
    const float* pvv = pvV + (b*NVTX + v)*HID;

    float h1[HID];
#pragma unroll
    for (int i = 0; i < HID; i += 4) {
        float4 av = *(const float4*)(pa + i);
        float4 bv = *(const float4*)(pvv + i);
        h1[i+0] = fmaxf(av.x + bv.x, 0.f);
        h1[i+1] = fmaxf(av.y + bv.y, 0.f);
        h1[i+2] = fmaxf(av.z + bv.z, 0.f);
        h1[i+3] = fmaxf(av.w + bv.w, 0.f);
    }

    float h2[HID];
#pragma unroll
    for (int q = 0; q < HID/4; ++q) {
        float4 acc = *(const float4*)(sb2 + q*4);
#pragma unroll
        for (int i = 0; i < HID; ++i) {
            float4 w = *(const float4*)(sw2 + i*HID + q*4);
            float hv = h1[i];
            acc.x += hv*w.x; acc.y += hv*w.y; acc.z += hv*w.z; acc.w += hv*w.w;
        }
        h2[q*4+0] = fmaxf(acc.x, 0.f);
        h2[q*4+1] = fmaxf(acc.y, 0.f);
        h2[q*4+2] = fmaxf(acc.z, 0.f);
        h2[q*4+3] = fmaxf(acc.w, 0.f);
    }

    float* o = Epv + (b*NPART + p)*DE;
#pragma unroll
    for (int q = 0; q < DE/4; ++q) {
        float4 acc = *(const float4*)(sb3 + q*4);
#pragma unroll
        for (int i = 0; i < HID; ++i) {
            float4 w = *(const float4*)(sw3 + i*DE + q*4);
            float hv = h2[i];
            acc.x += hv*w.x; acc.y += hv*w.y; acc.z += hv*w.z; acc.w += hv*w.w;
        }
        atomicAdd(o + q*4+0, fmaxf(acc.x, 0.f));
        atomicAdd(o + q*4+1, fmaxf(acc.y, 0.f));
        atomicAdd(o + q*4+2, fmaxf(acc.z, 0.f));
        atomicAdd(o + q*4+3, fmaxf(acc.w, 0.f));
    }
}

// ---------------------------------------------------------------------------
// Stage D: object MLP + sum over particles + fc head. Block per b, lane = p.
// ---------------------------------------------------------------------------
__global__ __launch_bounds__(64) void stageD_kernel(
    const float* __restrict__ x, const float* __restrict__ Epp, const float* __restrict__ Epv,
    const float* __restrict__ w1g, const float* __restrict__ b1g,
    const float* __restrict__ w2g, const float* __restrict__ b2g,
    const float* __restrict__ w3g, const float* __restrict__ b3g,
    const float* __restrict__ fcw, const float* __restrict__ fcb,
    float* __restrict__ out)
{
    __shared__ __align__(16) float sw1[HID*HID];
    __shared__ __align__(16) float sw2[HID*HID];
    __shared__ __align__(16) float sw3[HID*DO];
    __shared__ __align__(16) float sb1[HID];
    __shared__ __align__(16) float sb2[HID];
    __shared__ __align__(16) float sb3[DO];
    __shared__ float sfcw[DO*NCLS];
    __shared__ float sfcb[NCLS];
    for (int i = threadIdx.x; i < HID*HID; i += 64) { sw1[i] = w1g[i]; sw2[i] = w2g[i]; }
    for (int i = threadIdx.x; i < HID*DO;  i += 64) sw3[i] = w3g[i];
    if (threadIdx.x < HID) { sb1[threadIdx.x] = b1g[threadIdx.x]; sb2[threadIdx.x] = b2g[threadIdx.x]; }
    if (threadIdx.x < DO)  sb3[threadIdx.x] = b3g[threadIdx.x];
    if (threadIdx.x < DO*NCLS) sfcw[threadIdx.x] = fcw[threadIdx.x];
    if (threadIdx.x < NCLS) sfcb[threadIdx.x] = fcb[threadIdx.x];
    __syncthreads();

    int b = blockIdx.x;
    int p = threadIdx.x;

    float cin[HID];
    if (p < NPART) {
#pragma unroll
        for (int f = 0; f < PFEAT; ++f) cin[f] = x[(b*PFEAT + f)*NPART + p];
#pragma unroll
        for (int k = 0; k < DE; ++k) {
            cin[PFEAT + k]      = Epp[(b*NPART + p)*DE + k];
            cin[PFEAT + DE + k] = Epv[(b*NPART + p)*DE + k];
        }
    } else {
#pragma unroll
        for (int i = 0; i < HID; ++i) cin[i] = 0.f;
    }

    float h1[HID];
#pragma unroll
    for (int q = 0; q < HID/4; ++q) {
        float4 acc = *(const float4*)(sb1 + q*4);
#pragma unroll
        for (int i = 0; i < HID; ++i) {
            float4 w = *(const float4*)(sw1 + i*HID + q*4);
            float hv = cin[i];
            acc.x += hv*w.x; acc.y += hv*w.y; acc.z += hv*w.z; acc.w += hv*w.w;
        }
        h1[q*4+0] = fmaxf(acc.x, 0.f);
        h1[q*4+1] = fmaxf(acc.y, 0.f);
        h1[q*4+2] = fmaxf(acc.z, 0.f);
        h1[q*4+3] = fmaxf(acc.w, 0.f);
    }

    float h2[HID];
#pragma unroll
    for (int q = 0; q < HID/4; ++q) {
        float4 acc = *(const float4*)(sb2 + q*4);
#pragma unroll
        for (int i = 0; i < HID; ++i) {
            float4 w = *(const float4*)(sw2 + i*HID + q*4);
            float hv = h1[i];
            acc.x += hv*w.x; acc.y += hv*w.y; acc.z += hv*w.z; acc.w += hv*w.w;
        }
        h2[q*4+0] = fmaxf(acc.x, 0.f);
        h2[q*4+1] = fmaxf(acc.y, 0.f);
        h2[q*4+2] = fmaxf(acc.z, 0.f);
        h2[q*4+3] = fmaxf(acc.w, 0.f);
    }

    float o[DO];
#pragma unroll
    for (int q = 0; q < DO/4; ++q) {
        float4 acc = *(const float4*)(sb3 + q*4);
#pragma unroll
        for (int i = 0; i < HID; ++i) {
            float4 w = *(const float4*)(sw3 + i*DO + q*4);
            float hv = h2[i];
            acc.x += hv*w.x; acc.y += hv*w.y; acc.z += hv*w.z; acc.w += hv*w.w;
        }
        o[q*4+0] = fmaxf(acc.x, 0.f);
        o[q*4+1] = fmaxf(acc.y, 0.f);
        o[q*4+2] = fmaxf(acc.z, 0.f);
        o[q*4+3] = fmaxf(acc.w, 0.f);
    }

    if (p >= NPART) {
#pragma unroll
        for (int k = 0; k < DO; ++k) o[k] = 0.f;
    }

#pragma unroll
    for (int k = 0; k < DO; ++k) {
        float v = o[k];
        v += __shfl_xor(v, 1);
        v += __shfl_xor(v, 2);
        v += __shfl_xor(v, 4);
        v += __shfl_xor(v, 8);
        v += __shfl_xor(v, 16);
        v += __shfl_xor(v, 32);
        o[k] = v;
    }
    if (p == 0) {
        float o0 = sfcb[0], o1 = sfcb[1];
#pragma unroll
        for (int k = 0; k < DO; ++k) {
            o0 += o[k] * sfcw[k*NCLS + 0];
            o1 += o[k] * sfcw[k*NCLS + 1];
        }
        out[b*NCLS + 0] = o0;
        out[b*NCLS + 1] = o1;
    }
}

// ---------------------------------------------------------------------------
extern "C" void kernel_launch(void* const* d_in, const int* in_sizes, int n_in,
                              void* d_out, int out_size, void* d_ws, size_t ws_size,
                              hipStream_t stream)
{
    const float* x     = (const float*)d_in[0];
    const float* y     = (const float*)d_in[1];
    const float* fr_w1 = (const float*)d_in[2];
    const float* fr_b1 = (const float*)d_in[3];
    const float* fr_w2 = (const float*)d_in[4];
    const float* fr_b2 = (const float*)d_in[5];
    const float* fr_w3 = (const float*)d_in[6];
    const float* fr_b3 = (const float*)d_in[7];
    const float* pv_w1 = (const float*)d_in[8];
    const float* pv_b1 = (const float*)d_in[9];
    const float* pv_w2 = (const float*)d_in[10];
    const float* pv_b2 = (const float*)d_in[11];
    const float* pv_w3 = (const float*)d_in[12];
    const float* pv_b3 = (const float*)d_in[13];
    const float* fo_w1 = (const float*)d_in[14];
    const float* fo_b1 = (const float*)d_in[15];
    const float* fo_w2 = (const float*)d_in[16];
    const float* fo_b2 = (const float*)d_in[17];
    const float* fo_w3 = (const float*)d_in[18];
    const float* fo_b3 = (const float*)d_in[19];
    const float* fc_w  = (const float*)d_in[20];
    const float* fc_b  = (const float*)d_in[21];
    float* out = (float*)d_out;

    float* ws  = (float*)d_ws;
    float* frA = ws;                               // BATCH*NPART*HID
    float* frB = frA + BATCH*NPART*HID;            // BATCH*NPART*HID
    float* pvA = frB + BATCH*NPART*HID;            // BATCH*NPART*HID
    float* pvV = pvA + BATCH*NPART*HID;            // BATCH*NVTX*HID
    float* Epp = pvV + BATCH*NVTX*HID;             // BATCH*NPART*DE
    float* Epv = Epp + BATCH*NPART*DE;             // BATCH*NPART*DE

    hipMemsetAsync(Epv, 0, (size_t)BATCH*NPART*DE*sizeof(float), stream);

    stageA_kernel <<<BATCH*NPART, 64, 0, stream>>>(x, fr_w1, pv_w1, frA, frB, pvA);
    stageA2_kernel<<<BATCH, 64, 0, stream>>>(y, pv_w1, pv_b1, pvV);
    stageB_kernel <<<BATCH*NPART/4, 256, 0, stream>>>(frA, frB, fr_b1, fr_w2, fr_b2, fr_w3, fr_b3, Epp);
    stageC_kernel <<<BATCH*NPART*NVTX/256, 256, 0, stream>>>(pvA, pvV, pv_w2, pv_b2, pv_w3, pv_b3, Epv);
    stageD_kernel <<<BATCH, 64, 0, stream>>>(x, Epp, Epv, fo_w1, fo_b1, fo_w2, fo_b2, fo_w3, fo_b3, fc_w, fc_b, out);
}

// Round 2
// 346.877 us; speedup vs baseline: 2.7025x; 2.7025x over previous
//
#include <hip/hip_runtime.h>

#define BATCH 512
#define NPART 60
#define PFEAT 20
#define SFEAT 14
#define NVTX  5
#define HID   60
#define DE    20
#define DO    24
#define NCLS  2
#define HP    64          // padded hidden stride (fp16 rows)
#define LDST  72          // LDS h2 row stride in halves (bank-conflict pad)

typedef _Float16 half8 __attribute__((ext_vector_type(8)));
typedef float    f32x4 __attribute__((ext_vector_type(4)));

// ---------------------------------------------------------------------------
// Stage A: per (b,p) layer-1 partials in fp16, rows padded to HP=64 with zeros.
//   frA[b,p,:] = xt[b,p] @ fr_w1[0:20] + fr_b1   (receiver part, bias folded)
//   frB[b,p,:] = xt[b,p] @ fr_w1[20:40]          (sender part)
//   pvA[b,p,:] = xt[b,p] @ pv_w1[0:20]           (particle part)
// ---------------------------------------------------------------------------
__global__ __launch_bounds__(64) void stageA_kernel(
    const float* __restrict__ x, const float* __restrict__ fr_w1,
    const float* __restrict__ fr_b1, const float* __restrict__ pv_w1,
    _Float16* __restrict__ frA, _Float16* __restrict__ frB, _Float16* __restrict__ pvA)
{
    int bp = blockIdx.x;                  // b*NPART + p
    int h  = threadIdx.x;
    int b = bp / NPART;
    int p = bp - b * NPART;
    if (h >= HID) {                       // zero the pad columns
        frA[bp*HP + h] = (_Float16)0.f;
        frB[bp*HP + h] = (_Float16)0.f;
        pvA[bp*HP + h] = (_Float16)0.f;
        return;
    }
    float xr[PFEAT];
#pragma unroll
    for (int f = 0; f < PFEAT; ++f) xr[f] = x[(b*PFEAT + f)*NPART + p];

    float a = fr_b1[h], s = 0.f, c = 0.f;
#pragma unroll
    for (int f = 0; f < PFEAT; ++f) {
        float xv = xr[f];
        a += xv * fr_w1[f*HID + h];
        s += xv * fr_w1[(PFEAT + f)*HID + h];
        c += xv * pv_w1[f*HID + h];
    }
    frA[bp*HP + h] = (_Float16)a;
    frB[bp*HP + h] = (_Float16)s;
    pvA[bp*HP + h] = (_Float16)c;
}

// ---------------------------------------------------------------------------
// Stage A2: per (b,v): pvV[b,v,:] = yt[b,v] @ pv_w1[20:34] + pv_b1 (fp16, padded)
// ---------------------------------------------------------------------------
__global__ __launch_bounds__(64) void stageA2_kernel(
    const float* __restrict__ y, const float* __restrict__ pv_w1,
    const float* __restrict__ pv_b1, _Float16* __restrict__ pvV)
{
    int b = blockIdx.x;
    int h = threadIdx.x;
#pragma unroll
    for (int v = 0; v < NVTX; ++v) {
        if (h >= HID) { pvV[(b*NVTX + v)*HP + h] = (_Float16)0.f; continue; }
        float acc = pv_b1[h];
#pragma unroll
        for (int f = 0; f < SFEAT; ++f)
            acc += y[(b*SFEAT + f)*NVTX + v] * pv_w1[(PFEAT + f)*HID + h];
        pvV[(b*NVTX + v)*HP + h] = (_Float16)acc;
    }
}

// ---------------------------------------------------------------------------
// Pack kernel: w2/w3 (fr and pv) into fp16 MFMA B-fragment layout.
// B-frag (16x16x32): lane L holds B[k = kk*32 + (L>>4)*8 + j][n = u*16 + (L&15)]
// layout: Wp[((u*2 + kk)*64 + L)*8 + j]
// ---------------------------------------------------------------------------
__global__ __launch_bounds__(256) void pack_kernel(
    const float* __restrict__ fr_w2, const float* __restrict__ fr_w3,
    const float* __restrict__ pv_w2, const float* __restrict__ pv_w3,
    _Float16* __restrict__ frW2p, _Float16* __restrict__ frW3p,
    _Float16* __restrict__ pvW2p, _Float16* __restrict__ pvW3p)
{
    for (int idx = threadIdx.x; idx < 4096; idx += 256) {   // w2: u<4
        int j  = idx & 7;
        int L  = (idx >> 3) & 63;
        int kk = (idx >> 9) & 1;
        int u  = idx >> 10;
        int k  = kk*32 + (L >> 4)*8 + j;
        int n  = u*16 + (L & 15);
        float v2f = (k < HID && n < HID) ? fr_w2[k*HID + n] : 0.f;
        float v2p = (k < HID && n < HID) ? pv_w2[k*HID + n] : 0.f;
        frW2p[idx] = (_Float16)v2f;
        pvW2p[idx] = (_Float16)v2p;
    }
    for (int idx = threadIdx.x; idx < 2048; idx += 256) {   // w3: u<2, n<20
        int j  = idx & 7;
        int L  = (idx >> 3) & 63;
        int kk = (idx >> 9) & 1;
        int u  = idx >> 10;
        int k  = kk*32 + (L >> 4)*8 + j;
        int n  = u*16 + (L & 15);
        float v3f = (k < HID && n < DE) ? fr_w3[k*DE + n] : 0.f;
        float v3p = (k < HID && n < DE) ? pv_w3[k*DE + n] : 0.f;
        frW3p[idx] = (_Float16)v3f;
        pvW3p[idx] = (_Float16)v3p;
    }
}

// ---------------------------------------------------------------------------
// Edge MLP (layers 2+3) via MFMA. One wave per group g.
// SENDER=true : g=(b,r), rows = 59 sender-edges, epilogue sums rows -> Epp[b,r,:]
// SENDER=false: g=(b,v), rows = 60 particles,   epilogue stores per-row fp16
// A-frag (16x16x32): lane L holds A[m = 16t + (L&15)][k = kk*32 + (L>>4)*8 + j]
// C-frag: lane L holds C[row = (L>>4)*4 + i][col = L&15] per 16x16 tile.
// ---------------------------------------------------------------------------
template<bool SENDER>
__global__ __launch_bounds__(64) void edge_mfma_kernel(
    const _Float16* __restrict__ uniBase,   // frA (b,r) or pvV (b,v), stride HP
    const _Float16* __restrict__ varBase,   // frB or pvA, NPART rows per b, stride HP
    const half8* __restrict__ w2p,          // [4][2][64] half8
    const half8* __restrict__ w3p,          // [2][2][64] half8
    const float* __restrict__ b2, const float* __restrict__ b3,
    float* __restrict__ outSum,             // Epp (SENDER)
    _Float16* __restrict__ outRows)         // Epv2 (!SENDER)
{
    __shared__ _Float16 lds_h2[64*LDST];

    const int GPB   = SENDER ? NPART : NVTX;
    const int VALID = SENDER ? (NPART-1) : NPART;

    int g    = blockIdx.x;
    int b    = g / GPB;
    int rv   = g - b*GPB;
    int lane = threadIdx.x;
    int m    = lane & 15;
    int q    = lane >> 4;

    const _Float16* uni = uniBase + (size_t)g * HP;
    const _Float16* var = varBase + (size_t)b * NPART * HP;

    int srcRow[4];
#pragma unroll
    for (int t = 0; t < 4; ++t) {
        int row = 16*t + m;
        int s;
        if (SENDER) s = (row < VALID) ? (row + (row >= rv)) : 0;
        else        s = (row < VALID) ? row : 0;
        srcRow[t] = s;
    }

    // ---- build layer-2 A fragments: h1 = relu(uni + var[srcRow]) ----
    half8 bA[4][2];
#pragma unroll
    for (int t = 0; t < 4; ++t) {
#pragma unroll
        for (int kk = 0; kk < 2; ++kk) {
            half8 u8 = *(const half8*)(uni + kk*32 + q*8);
            half8 v8 = *(const half8*)(var + (size_t)srcRow[t]*HP + kk*32 + q*8);
            half8 s8 = u8 + v8;
#pragma unroll
            for (int j = 0; j < 8; ++j) {
                _Float16 vj = s8[j];
                s8[j] = (vj > (_Float16)0.f) ? vj : (_Float16)0.f;
            }
            bA[t][kk] = s8;
        }
    }

    // ---- layer 2 MFMA: [64 x 64] @ [64 x 64] ----
    f32x4 zero4 = {0.f, 0.f, 0.f, 0.f};
    f32x4 acc2[4][4];
#pragma unroll
    for (int t = 0; t < 4; ++t)
#pragma unroll
        for (int u = 0; u < 4; ++u) acc2[t][u] = zero4;

#pragma unroll
    for (int u = 0; u < 4; ++u) {
        half8 w0 = w2p[(u*2 + 0)*64 + lane];
        half8 w1 = w2p[(u*2 + 1)*64 + lane];
#pragma unroll
        for (int t = 0; t < 4; ++t) {
            acc2[t][u] = __builtin_amdgcn_mfma_f32_16x16x32_f16(bA[t][0], w0, acc2[t][u], 0, 0, 0);
            acc2[t][u] = __builtin_amdgcn_mfma_f32_16x16x32_f16(bA[t][1], w1, acc2[t][u], 0, 0, 0);
        }
    }

    // ---- h2 = relu(acc2 + b2) -> LDS (C-layout -> A-layout transpose) ----
    float rb2[4];
#pragma unroll
    for (int u = 0; u < 4; ++u) {
        int col = u*16 + m;
        rb2[u] = (col < HID) ? b2[col] : 0.f;
    }
#pragma unroll
    for (int t = 0; t < 4; ++t)
#pragma unroll
        for (int u = 0; u < 4; ++u)
#pragma unroll
            for (int i = 0; i < 4; ++i) {
                float v = acc2[t][u][i] + rb2[u];
                v = fmaxf(v, 0.f);
                lds_h2[(16*t + 4*q + i)*LDST + u*16 + m] = (_Float16)v;
            }
    __syncthreads();   // single wave: forces lgkmcnt drain before reads

    // ---- layer 3 MFMA: [64 x 64] @ [64 x 32] ----
    half8 a3[4][2];
#pragma unroll
    for (int t = 0; t < 4; ++t)
#pragma unroll
        for (int kk = 0; kk < 2; ++kk)
            a3[t][kk] = *(const half8*)(lds_h2 + (16*t + m)*LDST + kk*32 + q*8);

    f32x4 acc3[4][2];
#pragma unroll
    for (int t = 0; t < 4; ++t)
#pragma unroll
        for (int u = 0; u < 2; ++u) acc3[t][u] = zero4;

#pragma unroll
    for (int u = 0; u < 2; ++u) {
        half8 w0 = w3p[(u*2 + 0)*64 + lane];
        half8 w1 = w3p[(u*2 + 1)*64 + lane];
#pragma unroll
        for (int t = 0; t < 4; ++t) {
            acc3[t][u] = __builtin_amdgcn_mfma_f32_16x16x32_f16(a3[t][0], w0, acc3[t][u], 0, 0, 0);
            acc3[t][u] = __builtin_amdgcn_mfma_f32_16x16x32_f16(a3[t][1], w1, acc3[t][u], 0, 0, 0);
        }
    }

    // ---- epilogue: e = relu(acc3 + b3), zero invalid rows ----
    float rb3[2];
#pragma unroll
    for (int u = 0; u < 2; ++u) {
        int col = u*16 + m;
        rb3[u] = (col < DE) ? b3[col] : 0.f;
    }

    if (SENDER) {
#pragma unroll
        for (int u = 0; u < 2; ++u) {
            float ps = 0.f;
#pragma unroll
            for (int t = 0; t < 4; ++t)
#pragma unroll
                for (int i = 0; i < 4; ++i) {
                    int row = 16*t + 4*q + i;
                    float v = acc3[t][u][i] + rb3[u];
                    v = fmaxf(v, 0.f);
                    if (row >= VALID) v = 0.f;
                    ps += v;
                }
            ps += __shfl_xor(ps, 16);
            ps += __shfl_xor(ps, 32);
            int col = u*16 + m;
            if (q == 0 && col < DE)
                outSum[(size_t)g*DE + col] = ps;
        }
    } else {
#pragma unroll
        for (int u = 0; u < 2; ++u) {
            int col = u*16 + m;
#pragma unroll
            for (int t = 0; t < 4; ++t)
#pragma unroll
                for (int i = 0; i < 4; ++i) {
                    int row = 16*t + 4*q + i;
                    float v = acc3[t][u][i] + rb3[u];
                    v = fmaxf(v, 0.f);
                    if (row < VALID && col < DE)
                        outRows[((size_t)g*64 + row)*DE + col] = (_Float16)v;
                }
        }
    }
}

// ---------------------------------------------------------------------------
// Stage D: object MLP + sum over particles + fc head. 4 batch items per block
// (one per wave), weights staged once per block. fp32.
// ---------------------------------------------------------------------------
__global__ __launch_bounds__(256) void stageD_kernel(
    const float* __restrict__ x, const float* __restrict__ Epp, const _Float16* __restrict__ Epv2,
    const float* __restrict__ w1g, const float* __restrict__ b1g,
    const float* __restrict__ w2g, const float* __restrict__ b2g,
    const float* __restrict__ w3g, const float* __restrict__ b3g,
    const float* __restrict__ fcw, const float* __restrict__ fcb,
    float* __restrict__ out)
{
    __shared__ __align__(16) float sw1[HID*HID];
    __shared__ __align__(16) float sw2[HID*HID];
    __shared__ __align__(16) float sw3[HID*DO];
    __shared__ __align__(16) float sb1[HID];
    __shared__ __align__(16) float sb2[HID];
    __shared__ __align__(16) float sb3[DO];
    __shared__ float sfcw[DO*NCLS];
    __shared__ float sfcb[NCLS];
    for (int i = threadIdx.x; i < HID*HID; i += 256) { sw1[i] = w1g[i]; sw2[i] = w2g[i]; }
    for (int i = threadIdx.x; i < HID*DO;  i += 256) sw3[i] = w3g[i];
    if (threadIdx.x < HID) { sb1[threadIdx.x] = b1g[threadIdx.x]; sb2[threadIdx.x] = b2g[threadIdx.x]; }
    if (threadIdx.x < DO)  sb3[threadIdx.x] = b3g[threadIdx.x];
    if (threadIdx.x < DO*NCLS) sfcw[threadIdx.x] = fcw[threadIdx.x];
    if (threadIdx.x < NCLS) sfcb[threadIdx.x] = fcb[threadIdx.x];
    __syncthreads();

    int b = blockIdx.x*4 + (threadIdx.x >> 6);
    int p = threadIdx.x & 63;
    int lane = p;

    float cin[HID];
    if (p < NPART) {
#pragma unroll
        for (int f = 0; f < PFEAT; ++f) cin[f] = x[(b*PFEAT + f)*NPART + p];
#pragma unroll
        for (int k = 0; k < DE; ++k) cin[PFEAT + k] = Epp[((size_t)b*NPART + p)*DE + k];
#pragma unroll
        for (int k = 0; k < DE; ++k) {
            float s = 0.f;
#pragma unroll
            for (int v = 0; v < NVTX; ++v)
                s += (float)Epv2[(((size_t)b*NVTX + v)*64 + p)*DE + k];
            cin[PFEAT + DE + k] = s;
        }
    } else {
#pragma unroll
        for (int i = 0; i < HID; ++i) cin[i] = 0.f;
    }

    float h1[HID];
#pragma unroll
    for (int qd = 0; qd < HID/4; ++qd) {
        float4 acc = *(const float4*)(sb1 + qd*4);
#pragma unroll
        for (int i = 0; i < HID; ++i) {
            float4 w = *(const float4*)(sw1 + i*HID + qd*4);
            float hv = cin[i];
            acc.x += hv*w.x; acc.y += hv*w.y; acc.z += hv*w.z; acc.w += hv*w.w;
        }
        h1[qd*4+0] = fmaxf(acc.x, 0.f);
        h1[qd*4+1] = fmaxf(acc.y, 0.f);
        h1[qd*4+2] = fmaxf(acc.z, 0.f);
        h1[qd*4+3] = fmaxf(acc.w, 0.f);
    }

    float h2[HID];
#pragma unroll
    for (int qd = 0; qd < HID/4; ++qd) {
        float4 acc = *(const float4*)(sb2 + qd*4);
#pragma unroll
        for (int i = 0; i < HID; ++i) {
            float4 w = *(const float4*)(sw2 + i*HID + qd*4);
            float hv = h1[i];
            acc.x += hv*w.x; acc.y += hv*w.y; acc.z += hv*w.z; acc.w += hv*w.w;
        }
        h2[qd*4+0] = fmaxf(acc.x, 0.f);
        h2[qd*4+1] = fmaxf(acc.y, 0.f);
        h2[qd*4+2] = fmaxf(acc.z, 0.f);
        h2[qd*4+3] = fmaxf(acc.w, 0.f);
    }

    float o[DO];
#pragma unroll
    for (int qd = 0; qd < DO/4; ++qd) {
        float4 acc = *(const float4*)(sb3 + qd*4);
#pragma unroll
        for (int i = 0; i < HID; ++i) {
            float4 w = *(const float4*)(sw3 + i*DO + qd*4);
            float hv = h2[i];
            acc.x += hv*w.x; acc.y += hv*w.y; acc.z += hv*w.z; acc.w += hv*w.w;
        }
        o[qd*4+0] = fmaxf(acc.x, 0.f);
        o[qd*4+1] = fmaxf(acc.y, 0.f);
        o[qd*4+2] = fmaxf(acc.z, 0.f);
        o[qd*4+3] = fmaxf(acc.w, 0.f);
    }

    if (p >= NPART) {
#pragma unroll
        for (int k = 0; k < DO; ++k) o[k] = 0.f;
    }

#pragma unroll
    for (int k = 0; k < DO; ++k) {
        float v = o[k];
        v += __shfl_xor(v, 1);
        v += __shfl_xor(v, 2);
        v += __shfl_xor(v, 4);
        v += __shfl_xor(v, 8);
        v += __shfl_xor(v, 16);
        v += __shfl_xor(v, 32);
        o[k] = v;
    }
    if (lane == 0) {
        float o0 = sfcb[0], o1 = sfcb[1];
#pragma unroll
        for (int k = 0; k < DO; ++k) {
            o0 += o[k] * sfcw[k*NCLS + 0];
            o1 += o[k] * sfcw[k*NCLS + 1];
        }
        out[b*NCLS + 0] = o0;
        out[b*NCLS + 1] = o1;
    }
}

// ---------------------------------------------------------------------------
extern "C" void kernel_launch(void* const* d_in, const int* in_sizes, int n_in,
                              void* d_out, int out_size, void* d_ws, size_t ws_size,
                              hipStream_t stream)
{
    const float* x     = (const float*)d_in[0];
    const float* y     = (const float*)d_in[1];
    const float* fr_w1 = (const float*)d_in[2];
    const float* fr_b1 = (const float*)d_in[3];
    const float* fr_w2 = (const float*)d_in[4];
    const float* fr_b2 = (const float*)d_in[5];
    const float* fr_w3 = (const float*)d_in[6];
    const float* fr_b3 = (const float*)d_in[7];
    const float* pv_w1 = (const float*)d_in[8];
    const float* pv_b1 = (const float*)d_in[9];
    const float* pv_w2 = (const float*)d_in[10];
    const float* pv_b2 = (const float*)d_in[11];
    const float* pv_w3 = (const float*)d_in[12];
    const float* pv_b3 = (const float*)d_in[13];
    const float* fo_w1 = (const float*)d_in[14];
    const float* fo_b1 = (const float*)d_in[15];
    const float* fo_w2 = (const float*)d_in[16];
    const float* fo_b2 = (const float*)d_in[17];
    const float* fo_w3 = (const float*)d_in[18];
    const float* fo_b3 = (const float*)d_in[19];
    const float* fc_w  = (const float*)d_in[20];
    const float* fc_b  = (const float*)d_in[21];
    float* out = (float*)d_out;

    // workspace layout (bytes), all segments 256B-aligned
    char* wsb = (char*)d_ws;
    size_t off = 0;
    auto alloc = [&](size_t bytes) { char* p = wsb + off; off += (bytes + 255) & ~(size_t)255; return p; };

    _Float16* frA  = (_Float16*)alloc((size_t)BATCH*NPART*HP*2);        // 3.93 MB
    _Float16* frB  = (_Float16*)alloc((size_t)BATCH*NPART*HP*2);        // 3.93 MB
    _Float16* pvA  = (_Float16*)alloc((size_t)BATCH*NPART*HP*2);        // 3.93 MB
    _Float16* pvV  = (_Float16*)alloc((size_t)BATCH*NVTX*HP*2);         // 0.33 MB
    float*    Epp  = (float*)   alloc((size_t)BATCH*NPART*DE*4);        // 2.46 MB
    _Float16* Epv2 = (_Float16*)alloc((size_t)BATCH*NVTX*64*DE*2);      // 6.55 MB
    _Float16* frW2p = (_Float16*)alloc(4096*2);
    _Float16* frW3p = (_Float16*)alloc(2048*2);
    _Float16* pvW2p = (_Float16*)alloc(4096*2);
    _Float16* pvW3p = (_Float16*)alloc(2048*2);

    pack_kernel<<<1, 256, 0, stream>>>(fr_w2, fr_w3, pv_w2, pv_w3, frW2p, frW3p, pvW2p, pvW3p);
    stageA_kernel<<<BATCH*NPART, 64, 0, stream>>>(x, fr_w1, fr_b1, pv_w1, frA, frB, pvA);
    stageA2_kernel<<<BATCH, 64, 0, stream>>>(y, pv_w1, pv_b1, pvV);

    edge_mfma_kernel<true><<<BATCH*NPART, 64, 0, stream>>>(
        frA, frB, (const half8*)frW2p, (const half8*)frW3p, fr_b2, fr_b3, Epp, nullptr);
    edge_mfma_kernel<false><<<BATCH*NVTX, 64, 0, stream>>>(
        pvV, pvA, (const half8*)pvW2p, (const half8*)pvW3p, pv_b2, pv_b3, nullptr, Epv2);

    stageD_kernel<<<BATCH/4, 256, 0, stream>>>(x, Epp, Epv2,
        fo_w1, fo_b1, fo_w2, fo_b2, fo_w3, fo_b3, fc_w, fc_b, out);
}

// Round 3
// 225.467 us; speedup vs baseline: 4.1578x; 1.5385x over previous
//
#include <hip/hip_runtime.h>

#define BATCH 512
#define NPART 60
#define PFEAT 20
#define SFEAT 14
#define NVTX  5
#define HID   60
#define DE    20
#define DO    24
#define NCLS  2
#define HP    64          // padded hidden stride (fp16 rows)
#define LDST  72          // LDS transpose row stride in halves (bank-conflict pad)

typedef _Float16 half8 __attribute__((ext_vector_type(8)));
typedef float    f32x4 __attribute__((ext_vector_type(4)));

// ---------------------------------------------------------------------------
// Stage A: per (b,p) layer-1 partials in fp16, rows padded to HP=64 with zeros.
// ---------------------------------------------------------------------------
__global__ __launch_bounds__(64) void stageA_kernel(
    const float* __restrict__ x, const float* __restrict__ fr_w1,
    const float* __restrict__ fr_b1, const float* __restrict__ pv_w1,
    _Float16* __restrict__ frA, _Float16* __restrict__ frB, _Float16* __restrict__ pvA)
{
    int bp = blockIdx.x;                  // b*NPART + p
    int h  = threadIdx.x;
    int b = bp / NPART;
    int p = bp - b * NPART;
    if (h >= HID) {                       // zero the pad columns
        frA[bp*HP + h] = (_Float16)0.f;
        frB[bp*HP + h] = (_Float16)0.f;
        pvA[bp*HP + h] = (_Float16)0.f;
        return;
    }
    float xr[PFEAT];
#pragma unroll
    for (int f = 0; f < PFEAT; ++f) xr[f] = x[(b*PFEAT + f)*NPART + p];

    float a = fr_b1[h], s = 0.f, c = 0.f;
#pragma unroll
    for (int f = 0; f < PFEAT; ++f) {
        float xv = xr[f];
        a += xv * fr_w1[f*HID + h];
        s += xv * fr_w1[(PFEAT + f)*HID + h];
        c += xv * pv_w1[f*HID + h];
    }
    frA[bp*HP + h] = (_Float16)a;
    frB[bp*HP + h] = (_Float16)s;
    pvA[bp*HP + h] = (_Float16)c;
}

// ---------------------------------------------------------------------------
// Stage A2: per (b,v): pvV[b,v,:] = yt[b,v] @ pv_w1[20:34] + pv_b1 (fp16, padded)
// ---------------------------------------------------------------------------
__global__ __launch_bounds__(64) void stageA2_kernel(
    const float* __restrict__ y, const float* __restrict__ pv_w1,
    const float* __restrict__ pv_b1, _Float16* __restrict__ pvV)
{
    int b = blockIdx.x;
    int h = threadIdx.x;
#pragma unroll
    for (int v = 0; v < NVTX; ++v) {
        if (h >= HID) { pvV[(b*NVTX + v)*HP + h] = (_Float16)0.f; continue; }
        float acc = pv_b1[h];
#pragma unroll
        for (int f = 0; f < SFEAT; ++f)
            acc += y[(b*SFEAT + f)*NVTX + v] * pv_w1[(PFEAT + f)*HID + h];
        pvV[(b*NVTX + v)*HP + h] = (_Float16)acc;
    }
}

// ---------------------------------------------------------------------------
// Pack kernel: all MFMA B-fragment weight tables in fp16.
// B-frag (16x16x32): lane L holds B[k = kk*32 + (L>>4)*8 + j][n = u*16 + (L&15)]
// layout: Wp[((u*2 + kk)*64 + L)*8 + j]
// 64x64 tables (u<4): fr_w2, pv_w2, fo_w1, fo_w2     (din x dout = 60x60)
// 64x32 tables (u<2): fr_w3, pv_w3 (60x20), fo_w3 (60x24)
// ---------------------------------------------------------------------------
__global__ __launch_bounds__(256) void pack_kernel(
    const float* __restrict__ fr_w2, const float* __restrict__ fr_w3,
    const float* __restrict__ pv_w2, const float* __restrict__ pv_w3,
    const float* __restrict__ fo_w1, const float* __restrict__ fo_w2,
    const float* __restrict__ fo_w3,
    _Float16* __restrict__ frW2p, _Float16* __restrict__ frW3p,
    _Float16* __restrict__ pvW2p, _Float16* __restrict__ pvW3p,
    _Float16* __restrict__ foW1p, _Float16* __restrict__ foW2p,
    _Float16* __restrict__ foW3p)
{
    for (int idx = threadIdx.x; idx < 4096; idx += 256) {   // 64x64: u<4
        int j  = idx & 7;
        int L  = (idx >> 3) & 63;
        int kk = (idx >> 9) & 1;
        int u  = idx >> 10;
        int k  = kk*32 + (L >> 4)*8 + j;
        int n  = u*16 + (L & 15);
        bool ok = (k < HID && n < HID);
        frW2p[idx] = (_Float16)(ok ? fr_w2[k*HID + n] : 0.f);
        pvW2p[idx] = (_Float16)(ok ? pv_w2[k*HID + n] : 0.f);
        foW1p[idx] = (_Float16)(ok ? fo_w1[k*HID + n] : 0.f);
        foW2p[idx] = (_Float16)(ok ? fo_w2[k*HID + n] : 0.f);
    }
    for (int idx = threadIdx.x; idx < 2048; idx += 256) {   // 64x32: u<2
        int j  = idx & 7;
        int L  = (idx >> 3) & 63;
        int kk = (idx >> 9) & 1;
        int u  = idx >> 10;
        int k  = kk*32 + (L >> 4)*8 + j;
        int n  = u*16 + (L & 15);
        frW3p[idx] = (_Float16)((k < HID && n < DE) ? fr_w3[k*DE + n] : 0.f);
        pvW3p[idx] = (_Float16)((k < HID && n < DE) ? pv_w3[k*DE + n] : 0.f);
        foW3p[idx] = (_Float16)((k < HID && n < DO) ? fo_w3[k*DO + n] : 0.f);
    }
}

// ---------------------------------------------------------------------------
// Edge MLP (layers 2+3) via MFMA. One wave per group g.
// SENDER=true : g=(b,r), rows = 59 sender-edges, epilogue sums rows -> Epp[b,r,:]
// SENDER=false: g=(b,v), rows = 60 particles,   epilogue stores per-row fp16
// A-frag (16x16x32): lane L holds A[m = 16t + (L&15)][k = kk*32 + (L>>4)*8 + j]
// C-frag: lane L holds C[row = (L>>4)*4 + i][col = L&15] per 16x16 tile.
// ---------------------------------------------------------------------------
template<bool SENDER>
__global__ __launch_bounds__(64) void edge_mfma_kernel(
    const _Float16* __restrict__ uniBase,   // frA (b,r) or pvV (b,v), stride HP
    const _Float16* __restrict__ varBase,   // frB or pvA, NPART rows per b, stride HP
    const half8* __restrict__ w2p,          // [4][2][64] half8
    const half8* __restrict__ w3p,          // [2][2][64] half8
    const float* __restrict__ b2, const float* __restrict__ b3,
    float* __restrict__ outSum,             // Epp (SENDER)
    _Float16* __restrict__ outRows)         // Epv2 (!SENDER)
{
    __shared__ _Float16 lds_h2[64*LDST];

    const int GPB   = SENDER ? NPART : NVTX;
    const int VALID = SENDER ? (NPART-1) : NPART;

    int g    = blockIdx.x;
    int b    = g / GPB;
    int rv   = g - b*GPB;
    int lane = threadIdx.x;
    int m    = lane & 15;
    int q    = lane >> 4;

    const _Float16* uni = uniBase + (size_t)g * HP;
    const _Float16* var = varBase + (size_t)b * NPART * HP;

    int srcRow[4];
#pragma unroll
    for (int t = 0; t < 4; ++t) {
        int row = 16*t + m;
        int s;
        if (SENDER) s = (row < VALID) ? (row + (row >= rv)) : 0;
        else        s = (row < VALID) ? row : 0;
        srcRow[t] = s;
    }

    // ---- build layer-2 A fragments: h1 = relu(uni + var[srcRow]) ----
    half8 bA[4][2];
#pragma unroll
    for (int t = 0; t < 4; ++t) {
#pragma unroll
        for (int kk = 0; kk < 2; ++kk) {
            half8 u8 = *(const half8*)(uni + kk*32 + q*8);
            half8 v8 = *(const half8*)(var + (size_t)srcRow[t]*HP + kk*32 + q*8);
            half8 s8 = u8 + v8;
#pragma unroll
            for (int j = 0; j < 8; ++j) {
                _Float16 vj = s8[j];
                s8[j] = (vj > (_Float16)0.f) ? vj : (_Float16)0.f;
            }
            bA[t][kk] = s8;
        }
    }

    // ---- layer 2 MFMA: [64 x 64] @ [64 x 64] ----
    f32x4 zero4 = {0.f, 0.f, 0.f, 0.f};
    f32x4 acc2[4][4];
#pragma unroll
    for (int t = 0; t < 4; ++t)
#pragma unroll
        for (int u = 0; u < 4; ++u) acc2[t][u] = zero4;

#pragma unroll
    for (int u = 0; u < 4; ++u) {
        half8 w0 = w2p[(u*2 + 0)*64 + lane];
        half8 w1 = w2p[(u*2 + 1)*64 + lane];
#pragma unroll
        for (int t = 0; t < 4; ++t) {
            acc2[t][u] = __builtin_amdgcn_mfma_f32_16x16x32_f16(bA[t][0], w0, acc2[t][u], 0, 0, 0);
            acc2[t][u] = __builtin_amdgcn_mfma_f32_16x16x32_f16(bA[t][1], w1, acc2[t][u], 0, 0, 0);
        }
    }

    // ---- h2 = relu(acc2 + b2) -> LDS (C-layout -> A-layout transpose) ----
    float rb2[4];
#pragma unroll
    for (int u = 0; u < 4; ++u) {
        int col = u*16 + m;
        rb2[u] = (col < HID) ? b2[col] : 0.f;
    }
#pragma unroll
    for (int t = 0; t < 4; ++t)
#pragma unroll
        for (int u = 0; u < 4; ++u)
#pragma unroll
            for (int i = 0; i < 4; ++i) {
                float v = acc2[t][u][i] + rb2[u];
                v = fmaxf(v, 0.f);
                lds_h2[(16*t + 4*q + i)*LDST + u*16 + m] = (_Float16)v;
            }
    __syncthreads();

    // ---- layer 3 MFMA: [64 x 64] @ [64 x 32] ----
    half8 a3[4][2];
#pragma unroll
    for (int t = 0; t < 4; ++t)
#pragma unroll
        for (int kk = 0; kk < 2; ++kk)
            a3[t][kk] = *(const half8*)(lds_h2 + (16*t + m)*LDST + kk*32 + q*8);

    f32x4 acc3[4][2];
#pragma unroll
    for (int t = 0; t < 4; ++t)
#pragma unroll
        for (int u = 0; u < 2; ++u) acc3[t][u] = zero4;

#pragma unroll
    for (int u = 0; u < 2; ++u) {
        half8 w0 = w3p[(u*2 + 0)*64 + lane];
        half8 w1 = w3p[(u*2 + 1)*64 + lane];
#pragma unroll
        for (int t = 0; t < 4; ++t) {
            acc3[t][u] = __builtin_amdgcn_mfma_f32_16x16x32_f16(a3[t][0], w0, acc3[t][u], 0, 0, 0);
            acc3[t][u] = __builtin_amdgcn_mfma_f32_16x16x32_f16(a3[t][1], w1, acc3[t][u], 0, 0, 0);
        }
    }

    // ---- epilogue: e = relu(acc3 + b3), zero invalid rows ----
    float rb3[2];
#pragma unroll
    for (int u = 0; u < 2; ++u) {
        int col = u*16 + m;
        rb3[u] = (col < DE) ? b3[col] : 0.f;
    }

    if (SENDER) {
#pragma unroll
        for (int u = 0; u < 2; ++u) {
            float ps = 0.f;
#pragma unroll
            for (int t = 0; t < 4; ++t)
#pragma unroll
                for (int i = 0; i < 4; ++i) {
                    int row = 16*t + 4*q + i;
                    float v = acc3[t][u][i] + rb3[u];
                    v = fmaxf(v, 0.f);
                    if (row >= VALID) v = 0.f;
                    ps += v;
                }
            ps += __shfl_xor(ps, 16);
            ps += __shfl_xor(ps, 32);
            int col = u*16 + m;
            if (q == 0 && col < DE)
                outSum[(size_t)g*DE + col] = ps;
        }
    } else {
#pragma unroll
        for (int u = 0; u < 2; ++u) {
            int col = u*16 + m;
#pragma unroll
            for (int t = 0; t < 4; ++t)
#pragma unroll
                for (int i = 0; i < 4; ++i) {
                    int row = 16*t + 4*q + i;
                    float v = acc3[t][u][i] + rb3[u];
                    v = fmaxf(v, 0.f);
                    if (row < VALID && col < DE)
                        outRows[((size_t)g*64 + row)*DE + col] = (_Float16)v;
                }
        }
    }
}

// ---------------------------------------------------------------------------
// Prep: gather cin[b*NPART+p][64] = fp16 [ x(20) | Epp(20) | sum_v Epv(20) | 0 ]
// ---------------------------------------------------------------------------
__global__ __launch_bounds__(256) void prep_kernel(
    const float* __restrict__ x, const float* __restrict__ Epp,
    const _Float16* __restrict__ Epv2, _Float16* __restrict__ cin)
{
    int idx = blockIdx.x*256 + threadIdx.x;   // BATCH*NPART*64 total
    int bp = idx >> 6;
    int k  = idx & 63;
    int b  = bp / NPART;
    int p  = bp - b*NPART;

    float v;
    if (k < PFEAT) {
        v = x[(b*PFEAT + k)*NPART + p];
    } else if (k < PFEAT + DE) {
        v = Epp[(size_t)bp*DE + (k - PFEAT)];
    } else if (k < PFEAT + 2*DE) {
        int c = k - PFEAT - DE;
        float s = 0.f;
#pragma unroll
        for (int vv = 0; vv < NVTX; ++vv)
            s += (float)Epv2[(((size_t)b*NVTX + vv)*64 + p)*DE + c];
        v = s;
    } else {
        v = 0.f;
    }
    cin[(size_t)bp*HP + k] = (_Float16)v;
}

// ---------------------------------------------------------------------------
// Stage D via MFMA: object MLP (60->60->60->24) + particle sum + fc head.
// One wave per batch item b. Same fragment scheme as edge kernel.
// ---------------------------------------------------------------------------
__global__ __launch_bounds__(64) void stageD_mfma_kernel(
    const _Float16* __restrict__ cin,
    const half8* __restrict__ w1p, const half8* __restrict__ w2p,
    const half8* __restrict__ w3p,
    const float* __restrict__ b1, const float* __restrict__ b2,
    const float* __restrict__ b3,
    const float* __restrict__ fcw, const float* __restrict__ fcb,
    float* __restrict__ out)
{
    __shared__ _Float16 lds_t[64*LDST];

    int b    = blockIdx.x;
    int lane = threadIdx.x;
    int m    = lane & 15;
    int q    = lane >> 4;

    int srcRow[4];
#pragma unroll
    for (int t = 0; t < 4; ++t) {
        int row = 16*t + m;
        srcRow[t] = (row < NPART) ? row : 0;
    }

    const _Float16* base = cin + (size_t)b * NPART * HP;

    // ---- layer 1 A-frags straight from cin ----
    half8 a1[4][2];
#pragma unroll
    for (int t = 0; t < 4; ++t)
#pragma unroll
        for (int kk = 0; kk < 2; ++kk)
            a1[t][kk] = *(const half8*)(base + (size_t)srcRow[t]*HP + kk*32 + q*8);

    f32x4 zero4 = {0.f, 0.f, 0.f, 0.f};

    // ---- layer 1 MFMA ----
    f32x4 acc[4][4];
#pragma unroll
    for (int t = 0; t < 4; ++t)
#pragma unroll
        for (int u = 0; u < 4; ++u) acc[t][u] = zero4;
#pragma unroll
    for (int u = 0; u < 4; ++u) {
        half8 w0 = w1p[(u*2 + 0)*64 + lane];
        half8 w1 = w1p[(u*2 + 1)*64 + lane];
#pragma unroll
        for (int t = 0; t < 4; ++t) {
            acc[t][u] = __builtin_amdgcn_mfma_f32_16x16x32_f16(a1[t][0], w0, acc[t][u], 0, 0, 0);
            acc[t][u] = __builtin_amdgcn_mfma_f32_16x16x32_f16(a1[t][1], w1, acc[t][u], 0, 0, 0);
        }
    }

    // ---- h1 -> LDS transpose ----
    float rb1[4];
#pragma unroll
    for (int u = 0; u < 4; ++u) {
        int col = u*16 + m;
        rb1[u] = (col < HID) ? b1[col] : 0.f;
    }
#pragma unroll
    for (int t = 0; t < 4; ++t)
#pragma unroll
        for (int u = 0; u < 4; ++u)
#pragma unroll
            for (int i = 0; i < 4; ++i) {
                float v = acc[t][u][i] + rb1[u];
                lds_t[(16*t + 4*q + i)*LDST + u*16 + m] = (_Float16)fmaxf(v, 0.f);
            }
    __syncthreads();

    half8 a2[4][2];
#pragma unroll
    for (int t = 0; t < 4; ++t)
#pragma unroll
        for (int kk = 0; kk < 2; ++kk)
            a2[t][kk] = *(const half8*)(lds_t + (16*t + m)*LDST + kk*32 + q*8);
    __syncthreads();

    // ---- layer 2 MFMA ----
#pragma unroll
    for (int t = 0; t < 4; ++t)
#pragma unroll
        for (int u = 0; u < 4; ++u) acc[t][u] = zero4;
#pragma unroll
    for (int u = 0; u < 4; ++u) {
        half8 w0 = w2p[(u*2 + 0)*64 + lane];
        half8 w1 = w2p[(u*2 + 1)*64 + lane];
#pragma unroll
        for (int t = 0; t < 4; ++t) {
            acc[t][u] = __builtin_amdgcn_mfma_f32_16x16x32_f16(a2[t][0], w0, acc[t][u], 0, 0, 0);
            acc[t][u] = __builtin_amdgcn_mfma_f32_16x16x32_f16(a2[t][1], w1, acc[t][u], 0, 0, 0);
        }
    }

    // ---- h2 -> LDS transpose ----
    float rb2[4];
#pragma unroll
    for (int u = 0; u < 4; ++u) {
        int col = u*16 + m;
        rb2[u] = (col < HID) ? b2[col] : 0.f;
    }
#pragma unroll
    for (int t = 0; t < 4; ++t)
#pragma unroll
        for (int u = 0; u < 4; ++u)
#pragma unroll
            for (int i = 0; i < 4; ++i) {
                float v = acc[t][u][i] + rb2[u];
                lds_t[(16*t + 4*q + i)*LDST + u*16 + m] = (_Float16)fmaxf(v, 0.f);
            }
    __syncthreads();

    half8 a3[4][2];
#pragma unroll
    for (int t = 0; t < 4; ++t)
#pragma unroll
        for (int kk = 0; kk < 2; ++kk)
            a3[t][kk] = *(const half8*)(lds_t + (16*t + m)*LDST + kk*32 + q*8);

    // ---- layer 3 MFMA (cols 0..31, DO=24) ----
    f32x4 acc3[4][2];
#pragma unroll
    for (int t = 0; t < 4; ++t)
#pragma unroll
        for (int u = 0; u < 2; ++u) acc3[t][u] = zero4;
#pragma unroll
    for (int u = 0; u < 2; ++u) {
        half8 w0 = w3p[(u*2 + 0)*64 + lane];
        half8 w1 = w3p[(u*2 + 1)*64 + lane];
#pragma unroll
        for (int t = 0; t < 4; ++t) {
            acc3[t][u] = __builtin_amdgcn_mfma_f32_16x16x32_f16(a3[t][0], w0, acc3[t][u], 0, 0, 0);
            acc3[t][u] = __builtin_amdgcn_mfma_f32_16x16x32_f16(a3[t][1], w1, acc3[t][u], 0, 0, 0);
        }
    }

    // ---- epilogue: relu(+b3), sum valid rows, fc head ----
    float rb3[2];
#pragma unroll
    for (int u = 0; u < 2; ++u) {
        int col = u*16 + m;
        rb3[u] = (col < DO) ? b3[col] : 0.f;
    }
    float ps[2];
#pragma unroll
    for (int u = 0; u < 2; ++u) {
        float s = 0.f;
#pragma unroll
        for (int t = 0; t < 4; ++t)
#pragma unroll
            for (int i = 0; i < 4; ++i) {
                int row = 16*t + 4*q + i;
                float v = fmaxf(acc3[t][u][i] + rb3[u], 0.f);
                if (row < NPART) s += v;
            }
        s += __shfl_xor(s, 16);
        s += __shfl_xor(s, 32);
        ps[u] = s;     // column sum for col = u*16+m, replicated over q
    }

    float part[NCLS];
#pragma unroll
    for (int c = 0; c < NCLS; ++c) {
        float pc = 0.f;
        if (m < DO)      pc += ps[0] * fcw[m*NCLS + c];
        if (16 + m < DO) pc += ps[1] * fcw[(16 + m)*NCLS + c];
        pc += __shfl_xor(pc, 1);
        pc += __shfl_xor(pc, 2);
        pc += __shfl_xor(pc, 4);
        pc += __shfl_xor(pc, 8);
        part[c] = pc;
    }
    if (lane == 0) {
        out[b*NCLS + 0] = part[0] + fcb[0];
        out[b*NCLS + 1] = part[1] + fcb[1];
    }
}

// ---------------------------------------------------------------------------
extern "C" void kernel_launch(void* const* d_in, const int* in_sizes, int n_in,
                              void* d_out, int out_size, void* d_ws, size_t ws_size,
                              hipStream_t stream)
{
    const float* x     = (const float*)d_in[0];
    const float* y     = (const float*)d_in[1];
    const float* fr_w1 = (const float*)d_in[2];
    const float* fr_b1 = (const float*)d_in[3];
    const float* fr_w2 = (const float*)d_in[4];
    const float* fr_b2 = (const float*)d_in[5];
    const float* fr_w3 = (const float*)d_in[6];
    const float* fr_b3 = (const float*)d_in[7];
    const float* pv_w1 = (const float*)d_in[8];
    const float* pv_b1 = (const float*)d_in[9];
    const float* pv_w2 = (const float*)d_in[10];
    const float* pv_b2 = (const float*)d_in[11];
    const float* pv_w3 = (const float*)d_in[12];
    const float* pv_b3 = (const float*)d_in[13];
    const float* fo_w1 = (const float*)d_in[14];
    const float* fo_b1 = (const float*)d_in[15];
    const float* fo_w2 = (const float*)d_in[16];
    const float* fo_b2 = (const float*)d_in[17];
    const float* fo_w3 = (const float*)d_in[18];
    const float* fo_b3 = (const float*)d_in[19];
    const float* fc_w  = (const float*)d_in[20];
    const float* fc_b  = (const float*)d_in[21];
    float* out = (float*)d_out;

    char* wsb = (char*)d_ws;
    size_t off = 0;
    auto alloc = [&](size_t bytes) { char* p = wsb + off; off += (bytes + 255) & ~(size_t)255; return p; };

    _Float16* frA  = (_Float16*)alloc((size_t)BATCH*NPART*HP*2);        // 3.93 MB
    _Float16* frB  = (_Float16*)alloc((size_t)BATCH*NPART*HP*2);        // 3.93 MB
    _Float16* pvA  = (_Float16*)alloc((size_t)BATCH*NPART*HP*2);        // 3.93 MB
    _Float16* pvV  = (_Float16*)alloc((size_t)BATCH*NVTX*HP*2);         // 0.33 MB
    float*    Epp  = (float*)   alloc((size_t)BATCH*NPART*DE*4);        // 2.46 MB
    _Float16* Epv2 = (_Float16*)alloc((size_t)BATCH*NVTX*64*DE*2);      // 6.55 MB
    _Float16* cin  = (_Float16*)alloc((size_t)BATCH*NPART*HP*2);        // 3.93 MB
    _Float16* frW2p = (_Float16*)alloc(4096*2);
    _Float16* frW3p = (_Float16*)alloc(2048*2);
    _Float16* pvW2p = (_Float16*)alloc(4096*2);
    _Float16* pvW3p = (_Float16*)alloc(2048*2);
    _Float16* foW1p = (_Float16*)alloc(4096*2);
    _Float16* foW2p = (_Float16*)alloc(4096*2);
    _Float16* foW3p = (_Float16*)alloc(2048*2);

    pack_kernel<<<1, 256, 0, stream>>>(fr_w2, fr_w3, pv_w2, pv_w3, fo_w1, fo_w2, fo_w3,
                                       frW2p, frW3p, pvW2p, pvW3p, foW1p, foW2p, foW3p);
    stageA_kernel<<<BATCH*NPART, 64, 0, stream>>>(x, fr_w1, fr_b1, pv_w1, frA, frB, pvA);
    stageA2_kernel<<<BATCH, 64, 0, stream>>>(y, pv_w1, pv_b1, pvV);

    edge_mfma_kernel<true><<<BATCH*NPART, 64, 0, stream>>>(
        frA, frB, (const half8*)frW2p, (const half8*)frW3p, fr_b2, fr_b3, Epp, nullptr);
    edge_mfma_kernel<false><<<BATCH*NVTX, 64, 0, stream>>>(
        pvV, pvA, (const half8*)pvW2p, (const half8*)pvW3p, pv_b2, pv_b3, nullptr, Epv2);

    prep_kernel<<<(BATCH*NPART*HP)/256, 256, 0, stream>>>(x, Epp, Epv2, cin);

    stageD_mfma_kernel<<<BATCH, 64, 0, stream>>>(cin,
        (const half8*)foW1p, (const half8*)foW2p, (const half8*)foW3p,
        fo_b1, fo_b2, fo_b3, fc_w, fc_b, out);
}